// Round 4
// baseline (243.873 us; speedup 1.0000x reference)
//
#include <hip/hip_runtime.h>
#include <stdint.h>

typedef __attribute__((ext_vector_type(8))) short short8;
typedef __attribute__((ext_vector_type(4))) float f32x4;

#define MFMA16(A, B, C) __builtin_amdgcn_mfma_f32_16x16x32_bf16(A, B, C, 0, 0, 0)

// fp32 -> bf16 bits, round-to-nearest-even
__device__ __forceinline__ short f2bf(float f) {
    uint32_t u = __float_as_uint(f);
    u = (u + 0x7fffu + ((u >> 16) & 1u)) >> 16;
    return (short)u;
}
__device__ __forceinline__ float bf2f(short s) {
    return __uint_as_float(((uint32_t)(uint16_t)s) << 16);
}
// pack trunc-bf16(a) into low half, trunc-bf16(b) into high half: 1 v_perm_b32
__device__ __forceinline__ uint32_t pk_bf_trunc(float a, float b) {
    return __builtin_amdgcn_perm(__float_as_uint(b), __float_as_uint(a), 0x07060302u);
}

// load 8 contiguous fp32 from global, convert to bf16x8 fragment
__device__ __forceinline__ short8 ldg_f8_bf(const float* __restrict__ p) {
    float4 a = *(const float4*)p;
    float4 b = *(const float4*)(p + 4);
    short8 r;
    r[0] = f2bf(a.x); r[1] = f2bf(a.y); r[2] = f2bf(a.z); r[3] = f2bf(a.w);
    r[4] = f2bf(b.x); r[5] = f2bf(b.y); r[6] = f2bf(b.z); r[7] = f2bf(b.w);
    return r;
}

// ---------------------------------------------------------------------------
// Kernel 1: fused LayerNorm + q projection (MFMA) + depthwise 3x3 k,v convs.
// Grid (64 rows h, 4 batches), block 512.
// Outputs:
//   Qt[b][i][c] bf16, stride 64, q pre-scaled by log2(e)/8
//   KVg per (b,jt) tile of 8192 shorts: K [jl][c] s64 | V [c][sigma(jl)] s64
//   where sigma(j) = (j&15)*4 + (j>>4)  (k-axis permutation shared with P)
// ---------------------------------------------------------------------------
__global__ __launch_bounds__(512, 2) void k_lnqkv(
    const float* __restrict__ xg, const float* __restrict__ lng, const float* __restrict__ lnb,
    const float* __restrict__ wq, const float* __restrict__ bq,
    const float* __restrict__ wkg, const float* __restrict__ bk,
    const float* __restrict__ wvg, const float* __restrict__ bv,
    short* __restrict__ Qt, short* __restrict__ KVg)
{
    const int t    = threadIdx.x;
    const int wv   = t >> 6;      // wave 0..7
    const int lane = t & 63;
    const int l15  = lane & 15;
    const int quad = lane >> 4;
    const int h    = blockIdx.x;  // image row
    const int b    = blockIdx.y;

    __shared__ float xl[3 * 64 * 66];   // [dy*64+c][66]
    __shared__ short sb[64 * 72];       // union: {muL,rsL} -> xnt[w][c] -> vt[c][w]
    __shared__ float wkl[576], wvl[576], bkl[64], bvl[64];

    float* muL = (float*)sb;
    float* rsL = muL + 192;

    // P1: batch-load x rows h-1..h+1 into registers (single vmcnt wait), then LDS
    float rv[24];
    #pragma unroll
    for (int k = 0; k < 24; ++k) {
        int idx = t + (k << 9);
        int dy = idx >> 12, rem = idx & 4095;
        int c = rem >> 6, w = rem & 63;
        int hh = h + dy - 1;
        rv[k] = 0.f;
        if (hh >= 0 && hh < 64) rv[k] = xg[((b * 64 + c) * 64 + hh) * 64 + w];
    }
    for (int idx = t; idx < 576; idx += 512) { wkl[idx] = wkg[idx]; wvl[idx] = wvg[idx]; }
    if (t < 64) { bkl[t] = bk[t]; bvl[t] = bv[t]; }
    #pragma unroll
    for (int k = 0; k < 24; ++k) {
        int idx = t + (k << 9);
        int dy = idx >> 12, rem = idx & 4095;
        int c = rem >> 6, w = rem & 63;
        xl[(dy * 64 + c) * 66 + w] = rv[k];
    }
    __syncthreads();

    // P2: LN stats, 384 threads: 2 threads per (dy,w), 32 channels each + shfl
    if (t < 384) {
        int dy = t >> 7;
        int rem = t & 127;
        int w = rem >> 1, half = rem & 1;
        const float* col = &xl[(dy * 64 + half * 32) * 66 + w];
        float s = 0.f, ss = 0.f;
        #pragma unroll
        for (int cc = 0; cc < 32; ++cc) {
            float v = col[cc * 66];
            s += v; ss = fmaf(v, v, ss);
        }
        s  += __shfl_xor(s, 1);
        ss += __shfl_xor(ss, 1);
        if (half == 0) {
            float mu  = s * (1.f / 64.f);
            float var = ss * (1.f / 64.f) - mu * mu;
            muL[dy * 64 + w] = mu;
            rsL[dy * 64 + w] = rsqrtf(var + 1e-5f);
        }
    }
    __syncthreads();

    // P3: normalize in place (OOB rows -> 0 = conv zero padding)
    #pragma unroll
    for (int k = 0; k < 24; ++k) {
        int idx = t + (k << 9);
        int dy = idx >> 12, rem = idx & 4095;
        int c = rem >> 6, w = rem & 63;
        int hh = h + dy - 1;
        float v = xl[(dy * 64 + c) * 66 + w];
        int p = dy * 64 + w;
        v = (v - muL[p]) * rsL[p] * lng[c] + lnb[c];
        if (hh < 0 || hh >= 64) v = 0.f;
        xl[(dy * 64 + c) * 66 + w] = v;
    }
    __syncthreads();

    // P4: build xnt[w][c] bf16 (center row), stride 72
    {
        short* xnt = sb;
        int c = t & 63;
        #pragma unroll
        for (int k = 0; k < 8; ++k) {
            int w = wv + (k << 3);
            xnt[w * 72 + c] = f2bf(xl[(64 + c) * 66 + w]);
        }
    }
    __syncthreads();

    // P5: q = xn^T * wq^T via MFMA. 8 waves: wave=(tile 0..3, half 0..1).
    {
        const short* xnt = sb;
        const int tile = wv >> 1, half = wv & 1;
        short8 af[2];
        #pragma unroll
        for (int kc = 0; kc < 2; ++kc)
            af[kc] = *(const short8*)&xnt[(tile * 16 + l15) * 72 + kc * 32 + quad * 8];
        f32x4 acc[2];
        acc[0] = (f32x4){0.f, 0.f, 0.f, 0.f};
        acc[1] = (f32x4){0.f, 0.f, 0.f, 0.f};
        #pragma unroll
        for (int kc = 0; kc < 2; ++kc) {
            #pragma unroll
            for (int ntl = 0; ntl < 2; ++ntl) {
                int nt = half * 2 + ntl;
                short8 bf = ldg_f8_bf(&wq[(nt * 16 + l15) * 64 + kc * 32 + quad * 8]);
                acc[ntl] = MFMA16(af[kc], bf, acc[ntl]);
            }
        }
        const float c1 = 0.18033688011112042f;  // log2(e)/8 folded into q
        #pragma unroll
        for (int ntl = 0; ntl < 2; ++ntl) {
            int o = (half * 2 + ntl) * 16 + l15;
            float bqv = bq[o];
            #pragma unroll
            for (int r = 0; r < 4; ++r) {
                int w = tile * 16 + quad * 4 + r;
                Qt[((b * 4096 + h * 64 + w) << 6) + o] = f2bf((acc[ntl][r] + bqv) * c1);
            }
        }
    }
    __syncthreads();  // xnt reads done before vt overwrite

    // P6: depthwise 3x3. Lanes vary c; each thread 8 w at fixed c.
    {
        short* vt = sb;
        int c  = t & 63;
        int w0 = wv << 3;
        float wk9[9], wv9[9];
        #pragma unroll
        for (int q = 0; q < 9; ++q) { wk9[q] = wkl[c * 9 + q]; wv9[q] = wvl[c * 9 + q]; }
        float acck[8], accv[8];
        #pragma unroll
        for (int j = 0; j < 8; ++j) { acck[j] = bkl[c]; accv[j] = bvl[c]; }
        #pragma unroll
        for (int dy = 0; dy < 3; ++dy) {
            const float* row = &xl[(dy * 64 + c) * 66];
            float r[10];
            r[0] = (w0 == 0) ? 0.f : row[w0 - 1];
            #pragma unroll
            for (int j = 0; j < 8; ++j) r[j + 1] = row[w0 + j];
            r[9] = (w0 == 56) ? 0.f : row[w0 + 8];
            #pragma unroll
            for (int j = 0; j < 8; ++j) {
                acck[j] += wk9[0 + dy * 3] * r[j] + wk9[1 + dy * 3] * r[j + 1] + wk9[2 + dy * 3] * r[j + 2];
                accv[j] += wv9[0 + dy * 3] * r[j] + wv9[1 + dy * 3] * r[j + 1] + wv9[2 + dy * 3] * r[j + 2];
            }
        }
        long tb = (long)(b * 64 + h) * 8192;
        #pragma unroll
        for (int j = 0; j < 8; ++j)
            KVg[tb + (w0 + j) * 64 + c] = f2bf(acck[j]);   // K [jl][c], coalesced in c
        #pragma unroll
        for (int j = 0; j < 8; ++j)
            vt[c * 72 + w0 + j] = f2bf(accv[j]);           // V transpose staging
    }
    __syncthreads();

    // P7: V -> global [c][sigma(jl)]  (sigma matches P's packed-column layout)
    {
        const short* vt = sb;
        long tb = (long)(b * 64 + h) * 8192 + 4096;
        for (int idx = t; idx < 4096; idx += 512) {
            int c = idx >> 6, jl = idx & 63;
            int s = ((jl & 15) << 2) | (jl >> 4);
            KVg[tb + c * 64 + s] = vt[c * 72 + jl];
        }
    }
}

// ---------------------------------------------------------------------------
// Kernel 2: flash attention, no-max softmax (exp2, scale folded into Q),
// split-j x4. Grid (64 i-tiles of 64, 4 j-parts, 4 batches), block 128
// (2 waves, 32 q-rows each). Register-double-buffered KV (prefetch tile jt+1
// between rs0 and rs1 of tile jt), fully unrolled 16-iter loop -> forces
// ~210 live VGPRs of in-flight loads (launch_bounds(128,2): cap 256,
// 2 waves/SIMD). P pack via v_perm (trunc bf16) + sigma k-permutation ->
// 4 ds_write_b64 per rs. Zero barriers.
// ---------------------------------------------------------------------------
__global__ __launch_bounds__(128, 2) void k_attn(
    const short* __restrict__ Qt, const short* __restrict__ KVg,
    short* __restrict__ Ogb, float* __restrict__ Lg)
{
    const int t    = threadIdx.x;
    const int wv   = t >> 6;        // 0..1
    const int lane = t & 63;
    const int l15  = lane & 15;
    const int quad = lane >> 4;
    const int ti   = blockIdx.x;    // 64-row i-tile
    const int jp   = blockIdx.y;
    const int b    = blockIdx.z;
    const int iw   = ti * 64 + wv * 32;   // wave's first query row (owns 32)

    __shared__ short ldsP[2 * 16 * 72];
    short* myP = &ldsP[wv * 16 * 72];

    short8 qf[2][2];
    #pragma unroll
    for (int rs = 0; rs < 2; ++rs)
        #pragma unroll
        for (int kc = 0; kc < 2; ++kc)
            qf[rs][kc] = *(const short8*)&Qt[((b * 4096 + iw + rs * 16 + l15) << 6) + kc * 32 + quad * 8];

    f32x4 oacc[2][4];
    #pragma unroll
    for (int rs = 0; rs < 2; ++rs)
        #pragma unroll
        for (int nt = 0; nt < 4; ++nt) oacc[rs][nt] = (f32x4){0.f, 0.f, 0.f, 0.f};
    float Lp[2][4] = {{0.f, 0.f, 0.f, 0.f}, {0.f, 0.f, 0.f, 0.f}};

    const short* kvb = KVg + ((long)b * 64 + jp * 16) * 8192;
    const int koff = l15 * 64 + quad * 8;   // fragment lane offset (row l15 of 16-row group)

    short8 kf[2][4][2], vf[2][4][2];        // [buf][n][kc]
    // prologue: tile 0 -> buffer 0
    #pragma unroll
    for (int n = 0; n < 4; ++n)
        #pragma unroll
        for (int kc = 0; kc < 2; ++kc) {
            kf[0][n][kc] = *(const short8*)&kvb[n * 1024 + koff + kc * 32];
            vf[0][n][kc] = *(const short8*)&kvb[4096 + n * 1024 + koff + kc * 32];
        }

    #pragma unroll
    for (int jt = 0; jt < 16; ++jt) {
        const int cur = jt & 1, nxt = cur ^ 1;

        #pragma unroll
        for (int rs = 0; rs < 2; ++rs) {
            f32x4 sacc[4];
            #pragma unroll
            for (int n = 0; n < 4; ++n) sacc[n] = (f32x4){0.f, 0.f, 0.f, 0.f};
            #pragma unroll
            for (int kc = 0; kc < 2; ++kc)
                #pragma unroll
                for (int n = 0; n < 4; ++n)
                    sacc[n] = MFMA16(qf[rs][kc], kf[cur][n][kc], sacc[n]);

            // P = exp2(S) (no running max: |S_log2| <~ 9, fp32-safe)
            // pack 4 cols (n=0..3) per row into storage cols l15*4..+3 (sigma layout)
            #pragma unroll
            for (int r = 0; r < 4; ++r) {
                float p0 = __builtin_amdgcn_exp2f(sacc[0][r]);
                float p1 = __builtin_amdgcn_exp2f(sacc[1][r]);
                float p2 = __builtin_amdgcn_exp2f(sacc[2][r]);
                float p3 = __builtin_amdgcn_exp2f(sacc[3][r]);
                Lp[rs][r] += (p0 + p1) + (p2 + p3);
                uint2 pk;
                pk.x = pk_bf_trunc(p0, p1);
                pk.y = pk_bf_trunc(p2, p3);
                *(uint2*)&myP[(quad * 4 + r) * 72 + l15 * 4] = pk;
            }
            // wave-private relayout read (same-wave DS ordering, no barrier)
            short8 pf[2];
            #pragma unroll
            for (int kc = 0; kc < 2; ++kc)
                pf[kc] = *(const short8*)&myP[l15 * 72 + kc * 32 + quad * 8];
            #pragma unroll
            for (int kc = 0; kc < 2; ++kc)
                #pragma unroll
                for (int n = 0; n < 4; ++n)
                    oacc[rs][n] = MFMA16(pf[kc], vf[cur][n][kc], oacc[rs][n]);

            // after rs0: issue next tile's loads (covered by rs1's compute)
            if (rs == 0 && jt < 15) {
                const short* base = kvb + (jt + 1) * 8192;
                #pragma unroll
                for (int n = 0; n < 4; ++n)
                    #pragma unroll
                    for (int kc = 0; kc < 2; ++kc) {
                        kf[nxt][n][kc] = *(const short8*)&base[n * 1024 + koff + kc * 32];
                        vf[nxt][n][kc] = *(const short8*)&base[4096 + n * 1024 + koff + kc * 32];
                    }
            }
        }
    }

    // reduce row-sum partials over 16 column-lanes (once per kernel)
    const int p = b * 4 + jp;
    #pragma unroll
    for (int rs = 0; rs < 2; ++rs) {
        #pragma unroll
        for (int r = 0; r < 4; ++r) {
            #pragma unroll
            for (int off = 1; off < 16; off <<= 1)
                Lp[rs][r] += __shfl_xor(Lp[rs][r], off);
            int i = iw + rs * 16 + quad * 4 + r;
            if (l15 == 0) Lg[p * 4096 + i] = Lp[rs][r];
            #pragma unroll
            for (int nt = 0; nt < 4; ++nt)
                Ogb[((p * 4096 + i) << 6) + nt * 16 + l15] = f2bf(oacc[rs][nt][r]);
        }
    }
}

// ---------------------------------------------------------------------------
// Kernel 3: merge split-j partials + out = wo @ O^T + bo + x.
// Grid (256 i-tiles of 16, 4 batches), block 256.
// ---------------------------------------------------------------------------
__global__ __launch_bounds__(256, 4) void k_out(
    const short* __restrict__ Ogb, const float* __restrict__ Lg,
    const float* __restrict__ wo, const float* __restrict__ bo,
    const float* __restrict__ xg, float* __restrict__ out)
{
    const int t    = threadIdx.x;
    const int wv4  = t >> 6;
    const int lane = t & 63;
    const int l15  = lane & 15;
    const int quad = lane >> 4;
    const int i0   = blockIdx.x * 16;
    const int b    = blockIdx.y;

    // total L for this lane's B-row i = i0 + l15
    float Ls = 0.f;
    #pragma unroll
    for (int jp = 0; jp < 4; ++jp) Ls += Lg[(b * 4 + jp) * 4096 + i0 + l15];
    float invL = 1.0f / Ls;

    short8 af[2];
    #pragma unroll
    for (int kc = 0; kc < 2; ++kc)
        af[kc] = ldg_f8_bf(&wo[(wv4 * 16 + l15) * 64 + kc * 32 + quad * 8]);

    f32x4 acc = (f32x4){0.f, 0.f, 0.f, 0.f};
    #pragma unroll
    for (int kc = 0; kc < 2; ++kc) {
        float bs[8] = {0.f, 0.f, 0.f, 0.f, 0.f, 0.f, 0.f, 0.f};
        #pragma unroll
        for (int jp = 0; jp < 4; ++jp) {
            short8 ov = *(const short8*)&Ogb[(((b * 4 + jp) * 4096 + i0 + l15) << 6) + kc * 32 + quad * 8];
            #pragma unroll
            for (int e = 0; e < 8; ++e) bs[e] += bf2f(ov[e]);
        }
        short8 bfr;
        #pragma unroll
        for (int e = 0; e < 8; ++e) bfr[e] = f2bf(bs[e] * invL);
        acc = MFMA16(af[kc], bfr, acc);
    }
    #pragma unroll
    for (int r = 0; r < 4; ++r) {
        int o = wv4 * 16 + quad * 4 + r;
        long obase = ((long)(b * 64 + o)) << 12;
        out[obase + i0 + l15] = acc[r] + bo[o] + xg[obase + i0 + l15];
    }
}

extern "C" void kernel_launch(void* const* d_in, const int* in_sizes, int n_in,
                              void* d_out, int out_size, void* d_ws, size_t ws_size,
                              hipStream_t stream) {
    (void)in_sizes; (void)n_in; (void)out_size; (void)ws_size;
    const float* x   = (const float*)d_in[0];
    const float* lng = (const float*)d_in[1];
    const float* lnb = (const float*)d_in[2];
    const float* wq  = (const float*)d_in[3];
    const float* bq  = (const float*)d_in[4];
    const float* wk  = (const float*)d_in[5];
    const float* bk  = (const float*)d_in[6];
    const float* wvw = (const float*)d_in[7];
    const float* bv  = (const float*)d_in[8];
    const float* wo  = (const float*)d_in[9];
    const float* bo  = (const float*)d_in[10];
    float* out = (float*)d_out;

    short* Qt  = (short*)d_ws;              // 4*4096*64 bf16  = 2 MB
    short* KVg = Qt + 4 * 4096 * 64;        // 4*64*8192 bf16  = 4 MB
    short* Ogb = KVg + 4 * 64 * 8192;       // 16*4096*64 bf16 = 8 MB
    float* Lg  = (float*)(Ogb + 16 * 4096 * 64);  // 16*4096 f32 = 256 KB

    k_lnqkv<<<dim3(64, 4), 512, 0, stream>>>(x, lng, lnb, wq, bq, wk, bk, wvw, bv, Qt, KVg);
    k_attn<<<dim3(64, 4, 4), 128, 0, stream>>>(Qt, KVg, Ogb, Lg);
    k_out<<<dim3(256, 4), 256, 0, stream>>>(Ogb, Lg, wo, bo, x, out);
}

// Round 5
// 118.808 us; speedup vs baseline: 2.0527x; 2.0527x over previous
//
#include <hip/hip_runtime.h>
#include <stdint.h>

typedef __attribute__((ext_vector_type(8))) short short8;
typedef __attribute__((ext_vector_type(4))) float f32x4;

#define MFMA16(A, B, C) __builtin_amdgcn_mfma_f32_16x16x32_bf16(A, B, C, 0, 0, 0)

// fp32 -> bf16 bits, round-to-nearest-even
__device__ __forceinline__ short f2bf(float f) {
    uint32_t u = __float_as_uint(f);
    u = (u + 0x7fffu + ((u >> 16) & 1u)) >> 16;
    return (short)u;
}
__device__ __forceinline__ float bf2f(short s) {
    return __uint_as_float(((uint32_t)(uint16_t)s) << 16);
}
// pack trunc-bf16(a) lo, trunc-bf16(b) hi: 1 v_perm_b32
__device__ __forceinline__ uint32_t pk_bf_trunc(float a, float b) {
    return __builtin_amdgcn_perm(__float_as_uint(b), __float_as_uint(a), 0x07060302u);
}

// async global->LDS DMA, 16 B per lane (global_load_lds_dwordx4).
// LDS dest = wave-uniform base + lane*16 (m104); tracked by vmcnt, drained by
// the compiler's s_waitcnt before s_barrier (__syncthreads).
__device__ __forceinline__ void async_cp16(void* lds, const void* gm) {
    __builtin_amdgcn_global_load_lds(
        (const __attribute__((address_space(1))) unsigned int*)gm,
        (__attribute__((address_space(3))) unsigned int*)lds,
        16, 0, 0);
}

// XOR-swizzle within a 64x64 short tile: keeps ds_read_b128 fragment reads
// bank-balanced while the global->LDS image stays an identity copy.
__device__ __forceinline__ int swz(int row, int col) {
    return row * 64 + ((((col >> 3) ^ (row & 7)) << 3) | (col & 7));
}

// load 8 contiguous fp32 from global, convert to bf16x8 fragment
__device__ __forceinline__ short8 ldg_f8_bf(const float* __restrict__ p) {
    float4 a = *(const float4*)p;
    float4 b = *(const float4*)(p + 4);
    short8 r;
    r[0] = f2bf(a.x); r[1] = f2bf(a.y); r[2] = f2bf(a.z); r[3] = f2bf(a.w);
    r[4] = f2bf(b.x); r[5] = f2bf(b.y); r[6] = f2bf(b.z); r[7] = f2bf(b.w);
    return r;
}

// ---------------------------------------------------------------------------
// Kernel 1: fused LayerNorm + q projection (MFMA) + depthwise 3x3 k,v convs.
// Grid (64 rows h, 4 batches), block 512.
// Outputs:
//   Qt[b][i][c] bf16, stride 64, q pre-scaled by log2(e)/8
//   KVg per (b,jt) tile of 8192 shorts:
//     K part [0,4096):  element (jl, c)       at swz(jl, c)
//     V part [4096,..): element (c, sigma(jl)) at 4096 + swz(c, sigma(jl))
//   sigma(j) = (j&15)*4 + (j>>4)  (k-axis permutation shared with packed P)
// ---------------------------------------------------------------------------
__global__ __launch_bounds__(512, 2) void k_lnqkv(
    const float* __restrict__ xg, const float* __restrict__ lng, const float* __restrict__ lnb,
    const float* __restrict__ wq, const float* __restrict__ bq,
    const float* __restrict__ wkg, const float* __restrict__ bk,
    const float* __restrict__ wvg, const float* __restrict__ bv,
    short* __restrict__ Qt, short* __restrict__ KVg)
{
    const int t    = threadIdx.x;
    const int wv   = t >> 6;      // wave 0..7
    const int lane = t & 63;
    const int l15  = lane & 15;
    const int quad = lane >> 4;
    const int h    = blockIdx.x;  // image row
    const int b    = blockIdx.y;

    __shared__ float xl[3 * 64 * 66];   // [dy*64+c][66]
    __shared__ short sb[64 * 72];       // union: {muL,rsL} -> xnt[w][c] -> vt[c][w]
    __shared__ float wkl[576], wvl[576], bkl[64], bvl[64];

    float* muL = (float*)sb;
    float* rsL = muL + 192;

    // P1: batch-load x rows h-1..h+1 into registers (single vmcnt wait), then LDS
    float rv[24];
    #pragma unroll
    for (int k = 0; k < 24; ++k) {
        int idx = t + (k << 9);
        int dy = idx >> 12, rem = idx & 4095;
        int c = rem >> 6, w = rem & 63;
        int hh = h + dy - 1;
        rv[k] = 0.f;
        if (hh >= 0 && hh < 64) rv[k] = xg[((b * 64 + c) * 64 + hh) * 64 + w];
    }
    for (int idx = t; idx < 576; idx += 512) { wkl[idx] = wkg[idx]; wvl[idx] = wvg[idx]; }
    if (t < 64) { bkl[t] = bk[t]; bvl[t] = bv[t]; }
    #pragma unroll
    for (int k = 0; k < 24; ++k) {
        int idx = t + (k << 9);
        int dy = idx >> 12, rem = idx & 4095;
        int c = rem >> 6, w = rem & 63;
        xl[(dy * 64 + c) * 66 + w] = rv[k];
    }
    __syncthreads();

    // P2: LN stats, 384 threads: 2 threads per (dy,w), 32 channels each + shfl
    if (t < 384) {
        int dy = t >> 7;
        int rem = t & 127;
        int w = rem >> 1, half = rem & 1;
        const float* col = &xl[(dy * 64 + half * 32) * 66 + w];
        float s = 0.f, ss = 0.f;
        #pragma unroll
        for (int cc = 0; cc < 32; ++cc) {
            float v = col[cc * 66];
            s += v; ss = fmaf(v, v, ss);
        }
        s  += __shfl_xor(s, 1);
        ss += __shfl_xor(ss, 1);
        if (half == 0) {
            float mu  = s * (1.f / 64.f);
            float var = ss * (1.f / 64.f) - mu * mu;
            muL[dy * 64 + w] = mu;
            rsL[dy * 64 + w] = rsqrtf(var + 1e-5f);
        }
    }
    __syncthreads();

    // P3: normalize in place (OOB rows -> 0 = conv zero padding)
    #pragma unroll
    for (int k = 0; k < 24; ++k) {
        int idx = t + (k << 9);
        int dy = idx >> 12, rem = idx & 4095;
        int c = rem >> 6, w = rem & 63;
        int hh = h + dy - 1;
        float v = xl[(dy * 64 + c) * 66 + w];
        int p = dy * 64 + w;
        v = (v - muL[p]) * rsL[p] * lng[c] + lnb[c];
        if (hh < 0 || hh >= 64) v = 0.f;
        xl[(dy * 64 + c) * 66 + w] = v;
    }
    __syncthreads();

    // P4: build xnt[w][c] bf16 (center row), stride 72
    {
        short* xnt = sb;
        int c = t & 63;
        #pragma unroll
        for (int k = 0; k < 8; ++k) {
            int w = wv + (k << 3);
            xnt[w * 72 + c] = f2bf(xl[(64 + c) * 66 + w]);
        }
    }
    __syncthreads();

    // P5: q = xn^T * wq^T via MFMA. 8 waves: wave=(tile 0..3, half 0..1).
    {
        const short* xnt = sb;
        const int tile = wv >> 1, half = wv & 1;
        short8 af[2];
        #pragma unroll
        for (int kc = 0; kc < 2; ++kc)
            af[kc] = *(const short8*)&xnt[(tile * 16 + l15) * 72 + kc * 32 + quad * 8];
        f32x4 acc[2];
        acc[0] = (f32x4){0.f, 0.f, 0.f, 0.f};
        acc[1] = (f32x4){0.f, 0.f, 0.f, 0.f};
        #pragma unroll
        for (int kc = 0; kc < 2; ++kc) {
            #pragma unroll
            for (int ntl = 0; ntl < 2; ++ntl) {
                int nt = half * 2 + ntl;
                short8 bf = ldg_f8_bf(&wq[(nt * 16 + l15) * 64 + kc * 32 + quad * 8]);
                acc[ntl] = MFMA16(af[kc], bf, acc[ntl]);
            }
        }
        const float c1 = 0.18033688011112042f;  // log2(e)/8 folded into q
        #pragma unroll
        for (int ntl = 0; ntl < 2; ++ntl) {
            int o = (half * 2 + ntl) * 16 + l15;
            float bqv = bq[o];
            #pragma unroll
            for (int r = 0; r < 4; ++r) {
                int w = tile * 16 + quad * 4 + r;
                Qt[((b * 4096 + h * 64 + w) << 6) + o] = f2bf((acc[ntl][r] + bqv) * c1);
            }
        }
    }
    __syncthreads();  // xnt reads done before vt overwrite

    // P6: depthwise 3x3. Lanes vary c; each thread 8 w at fixed c.
    {
        short* vt = sb;
        int c  = t & 63;
        int w0 = wv << 3;
        float wk9[9], wv9[9];
        #pragma unroll
        for (int q = 0; q < 9; ++q) { wk9[q] = wkl[c * 9 + q]; wv9[q] = wvl[c * 9 + q]; }
        float acck[8], accv[8];
        #pragma unroll
        for (int j = 0; j < 8; ++j) { acck[j] = bkl[c]; accv[j] = bvl[c]; }
        #pragma unroll
        for (int dy = 0; dy < 3; ++dy) {
            const float* row = &xl[(dy * 64 + c) * 66];
            float r[10];
            r[0] = (w0 == 0) ? 0.f : row[w0 - 1];
            #pragma unroll
            for (int j = 0; j < 8; ++j) r[j + 1] = row[w0 + j];
            r[9] = (w0 == 56) ? 0.f : row[w0 + 8];
            #pragma unroll
            for (int j = 0; j < 8; ++j) {
                acck[j] += wk9[0 + dy * 3] * r[j] + wk9[1 + dy * 3] * r[j + 1] + wk9[2 + dy * 3] * r[j + 2];
                accv[j] += wv9[0 + dy * 3] * r[j] + wv9[1 + dy * 3] * r[j + 1] + wv9[2 + dy * 3] * r[j + 2];
            }
        }
        long tb = (long)(b * 64 + h) * 8192;
        #pragma unroll
        for (int j = 0; j < 8; ++j)
            KVg[tb + swz(w0 + j, c)] = f2bf(acck[j]);      // K swizzled, coalesced in c
        #pragma unroll
        for (int j = 0; j < 8; ++j)
            vt[c * 72 + w0 + j] = f2bf(accv[j]);           // V transpose staging
    }
    __syncthreads();

    // P7: V -> global at 4096 + swz(c, sigma(jl))
    {
        const short* vt = sb;
        long tb = (long)(b * 64 + h) * 8192 + 4096;
        for (int idx = t; idx < 4096; idx += 512) {
            int c = idx >> 6, jl = idx & 63;
            int s = ((jl & 15) << 2) | (jl >> 4);
            KVg[tb + swz(c, s)] = vt[c * 72 + jl];
        }
    }
}

// ---------------------------------------------------------------------------
// Kernel 2: flash attention, no-max softmax (exp2, scale folded into Q),
// split-j x4. Grid (64 i-tiles of 64, 4 j-parts, 4 batches), block 128
// (2 waves, 32 q-rows each). KV tiles DMA'd global->LDS via global_load_lds
// (no VGPR cost), double-buffered: one __syncthreads per tile both drains the
// previous prefetch and fences buffer reuse; prefetch of jt+1 issued right
// after, covered by a full tile of compute. Fragments via ds_read_b128 from
// the XOR-swizzled image (bank-balanced). jt loop kept rolled: no dynamic
// register-array indexing -> no scratch (R4 lesson).
// ---------------------------------------------------------------------------
__global__ __launch_bounds__(128, 2) void k_attn(
    const short* __restrict__ Qt, const short* __restrict__ KVg,
    short* __restrict__ Ogb, float* __restrict__ Lg)
{
    const int t    = threadIdx.x;
    const int wv   = t >> 6;        // 0..1
    const int lane = t & 63;
    const int l15  = lane & 15;
    const int quad = lane >> 4;
    const int ti   = blockIdx.x;    // 64-row i-tile
    const int jp   = blockIdx.y;
    const int b    = blockIdx.z;
    const int iw   = ti * 64 + wv * 32;   // wave's first query row (owns 32)

    __shared__ short kvb0[8192];          // 16 KB
    __shared__ short kvb1[8192];          // 16 KB
    __shared__ short ldsP[2 * 16 * 72];
    short* myP = &ldsP[wv * 16 * 72];

    const short* kvg = KVg + ((long)b * 64 + jp * 16) * 8192;

    short8 qf[2][2];
    #pragma unroll
    for (int rs = 0; rs < 2; ++rs)
        #pragma unroll
        for (int kc = 0; kc < 2; ++kc)
            qf[rs][kc] = *(const short8*)&Qt[((b * 4096 + iw + rs * 16 + l15) << 6) + kc * 32 + quad * 8];

    f32x4 oacc[2][4];
    #pragma unroll
    for (int rs = 0; rs < 2; ++rs)
        #pragma unroll
        for (int nt = 0; nt < 4; ++nt) oacc[rs][nt] = (f32x4){0.f, 0.f, 0.f, 0.f};
    float Lp[2][4] = {{0.f, 0.f, 0.f, 0.f}, {0.f, 0.f, 0.f, 0.f}};

    // prologue: DMA tile 0 -> kvb0 (each wave issues 8 of 16 x 1KB chunks)
    #pragma unroll
    for (int ii = 0; ii < 8; ++ii) {
        int inst = (wv << 3) + ii;
        async_cp16(kvb0 + inst * 512, kvg + inst * 512 + lane * 8);
    }

    const int xr = l15 & 7;

    #pragma unroll 1
    for (int jt = 0; jt < 16; ++jt) {
        short* cur = (jt & 1) ? kvb1 : kvb0;
        short* nxt = (jt & 1) ? kvb0 : kvb1;
        __syncthreads();   // drains DMA for cur (vmcnt) + fences reuse of nxt
        if (jt < 15) {
            const short* g = kvg + (jt + 1) * 8192;
            #pragma unroll
            for (int ii = 0; ii < 8; ++ii) {
                int inst = (wv << 3) + ii;
                async_cp16(nxt + inst * 512, g + inst * 512 + lane * 8);
            }
        }

        // fragment reads from swizzled LDS image
        short8 kf[4][2], vf[4][2];
        #pragma unroll
        for (int n = 0; n < 4; ++n) {
            int rbase = (n * 16 + l15) * 64;
            #pragma unroll
            for (int kc = 0; kc < 2; ++kc) {
                int cc = ((kc * 4 + quad) ^ xr) << 3;
                kf[n][kc] = *(const short8*)&cur[rbase + cc];
                vf[n][kc] = *(const short8*)&cur[4096 + rbase + cc];
            }
        }

        #pragma unroll
        for (int rs = 0; rs < 2; ++rs) {
            f32x4 sacc[4];
            #pragma unroll
            for (int n = 0; n < 4; ++n) sacc[n] = (f32x4){0.f, 0.f, 0.f, 0.f};
            #pragma unroll
            for (int kc = 0; kc < 2; ++kc)
                #pragma unroll
                for (int n = 0; n < 4; ++n)
                    sacc[n] = MFMA16(qf[rs][kc], kf[n][kc], sacc[n]);

            // P = exp2(S) (no running max: |S_log2| <~ 9, fp32-safe)
            // pack cols n=0..3 per row into storage cols l15*4..+3 (sigma layout)
            #pragma unroll
            for (int r = 0; r < 4; ++r) {
                float p0 = __builtin_amdgcn_exp2f(sacc[0][r]);
                float p1 = __builtin_amdgcn_exp2f(sacc[1][r]);
                float p2 = __builtin_amdgcn_exp2f(sacc[2][r]);
                float p3 = __builtin_amdgcn_exp2f(sacc[3][r]);
                Lp[rs][r] += (p0 + p1) + (p2 + p3);
                uint2 pk;
                pk.x = pk_bf_trunc(p0, p1);
                pk.y = pk_bf_trunc(p2, p3);
                *(uint2*)&myP[(quad * 4 + r) * 72 + l15 * 4] = pk;
            }
            // wave-private relayout read (same-wave DS ordering, no barrier)
            short8 pf[2];
            #pragma unroll
            for (int kc = 0; kc < 2; ++kc)
                pf[kc] = *(const short8*)&myP[l15 * 72 + kc * 32 + quad * 8];
            #pragma unroll
            for (int kc = 0; kc < 2; ++kc)
                #pragma unroll
                for (int n = 0; n < 4; ++n)
                    oacc[rs][n] = MFMA16(pf[kc], vf[n][kc], oacc[rs][n]);
        }
    }

    // reduce row-sum partials over 16 column-lanes (once per kernel)
    const int p = b * 4 + jp;
    #pragma unroll
    for (int rs = 0; rs < 2; ++rs) {
        #pragma unroll
        for (int r = 0; r < 4; ++r) {
            #pragma unroll
            for (int off = 1; off < 16; off <<= 1)
                Lp[rs][r] += __shfl_xor(Lp[rs][r], off);
            int i = iw + rs * 16 + quad * 4 + r;
            if (l15 == 0) Lg[p * 4096 + i] = Lp[rs][r];
            #pragma unroll
            for (int nt = 0; nt < 4; ++nt)
                Ogb[((p * 4096 + i) << 6) + nt * 16 + l15] = f2bf(oacc[rs][nt][r]);
        }
    }
}

// ---------------------------------------------------------------------------
// Kernel 3: merge split-j partials + out = wo @ O^T + bo + x.
// Grid (256 i-tiles of 16, 4 batches), block 256.
// ---------------------------------------------------------------------------
__global__ __launch_bounds__(256, 4) void k_out(
    const short* __restrict__ Ogb, const float* __restrict__ Lg,
    const float* __restrict__ wo, const float* __restrict__ bo,
    const float* __restrict__ xg, float* __restrict__ out)
{
    const int t    = threadIdx.x;
    const int wv4  = t >> 6;
    const int lane = t & 63;
    const int l15  = lane & 15;
    const int quad = lane >> 4;
    const int i0   = blockIdx.x * 16;
    const int b    = blockIdx.y;

    // total L for this lane's B-row i = i0 + l15
    float Ls = 0.f;
    #pragma unroll
    for (int jp = 0; jp < 4; ++jp) Ls += Lg[(b * 4 + jp) * 4096 + i0 + l15];
    float invL = 1.0f / Ls;

    short8 af[2];
    #pragma unroll
    for (int kc = 0; kc < 2; ++kc)
        af[kc] = ldg_f8_bf(&wo[(wv4 * 16 + l15) * 64 + kc * 32 + quad * 8]);

    f32x4 acc = (f32x4){0.f, 0.f, 0.f, 0.f};
    #pragma unroll
    for (int kc = 0; kc < 2; ++kc) {
        float bs[8] = {0.f, 0.f, 0.f, 0.f, 0.f, 0.f, 0.f, 0.f};
        #pragma unroll
        for (int jp = 0; jp < 4; ++jp) {
            short8 ov = *(const short8*)&Ogb[(((b * 4 + jp) * 4096 + i0 + l15) << 6) + kc * 32 + quad * 8];
            #pragma unroll
            for (int e = 0; e < 8; ++e) bs[e] += bf2f(ov[e]);
        }
        short8 bfr;
        #pragma unroll
        for (int e = 0; e < 8; ++e) bfr[e] = f2bf(bs[e] * invL);
        acc = MFMA16(af[kc], bfr, acc);
    }
    #pragma unroll
    for (int r = 0; r < 4; ++r) {
        int o = wv4 * 16 + quad * 4 + r;
        long obase = ((long)(b * 64 + o)) << 12;
        out[obase + i0 + l15] = acc[r] + bo[o] + xg[obase + i0 + l15];
    }
}

extern "C" void kernel_launch(void* const* d_in, const int* in_sizes, int n_in,
                              void* d_out, int out_size, void* d_ws, size_t ws_size,
                              hipStream_t stream) {
    (void)in_sizes; (void)n_in; (void)out_size; (void)ws_size;
    const float* x   = (const float*)d_in[0];
    const float* lng = (const float*)d_in[1];
    const float* lnb = (const float*)d_in[2];
    const float* wq  = (const float*)d_in[3];
    const float* bq  = (const float*)d_in[4];
    const float* wk  = (const float*)d_in[5];
    const float* bk  = (const float*)d_in[6];
    const float* wvw = (const float*)d_in[7];
    const float* bv  = (const float*)d_in[8];
    const float* wo  = (const float*)d_in[9];
    const float* bo  = (const float*)d_in[10];
    float* out = (float*)d_out;

    short* Qt  = (short*)d_ws;              // 4*4096*64 bf16  = 2 MB
    short* KVg = Qt + 4 * 4096 * 64;        // 4*64*8192 bf16  = 4 MB
    short* Ogb = KVg + 4 * 64 * 8192;       // 16*4096*64 bf16 = 8 MB
    float* Lg  = (float*)(Ogb + 16 * 4096 * 64);  // 16*4096 f32 = 256 KB

    k_lnqkv<<<dim3(64, 4), 512, 0, stream>>>(x, lng, lnb, wq, bq, wk, bk, wvw, bv, Qt, KVg);
    k_attn<<<dim3(64, 4, 4), 128, 0, stream>>>(Qt, KVg, Ogb, Lg);
    k_out<<<dim3(256, 4), 256, 0, stream>>>(Ogb, Lg, wo, bo, x, out);
}